// Round 10
// baseline (336.588 us; speedup 1.0000x reference)
//
#include <hip/hip_runtime.h>

#define N_NODES 30000
#define N_EDGES 150000
#define N_REL 10
#define DIM 256

#define SORT_BLOCKS 120
#define SORT_CHUNK ((N_EDGES + SORT_BLOCKS - 1) / SORT_BLOCKS)  // 1250

// LDS A-tile row stride: 280 shorts = 560 B (16B-aligned, breaks pow2 banks)
#define A_STRIDE 280

// prep kernel block ranges
#define PREP_XB 7500   // conv_x: 30000*256/4/256
#define PREP_WB 5376   // conv_w: 21*65536/256
#define PREP_ZB 118    // zero cnt: (30000+255)/256

typedef __attribute__((ext_vector_type(8))) short bf16x8;
typedef __attribute__((ext_vector_type(4))) float f32x4;

__device__ __forceinline__ unsigned short f2bf(float f) {
  union { float f; unsigned int u; } v; v.f = f;
  unsigned int u = v.u;
  unsigned int r = u + 0x7fffu + ((u >> 16) & 1u);  // RNE
  return (unsigned short)(r >> 16);
}

// ---- fused preprocessing: x->bf16, W->bf16 transposed, zero cnt ----------

__global__ void prep_kernel(const float* __restrict__ x,
                            const float* __restrict__ Wf,
                            const float* __restrict__ Wr,
                            const float* __restrict__ Ws,
                            unsigned short* __restrict__ xbf,
                            unsigned short* __restrict__ wt,
                            int* __restrict__ cnt) {
  int b = blockIdx.x;
  if (b < PREP_XB) {
    int idx = b * 256 + threadIdx.x;  // one float4 each, exact
    float4 v = reinterpret_cast<const float4*>(x)[idx];
    ushort4 o;
    o.x = f2bf(v.x); o.y = f2bf(v.y); o.z = f2bf(v.z); o.w = f2bf(v.w);
    reinterpret_cast<ushort4*>(xbf)[idx] = o;
  } else if (b < PREP_XB + PREP_WB) {
    int idx = (b - PREP_XB) * 256 + threadIdx.x;  // wt[b][o][i] = W_b[i][o]
    int bb = idx >> 16;
    int t = idx & 65535;
    int o = t >> 8, i = t & 255;
    const float* src = (bb < N_REL) ? (Wf + (size_t)bb * 65536)
                     : (bb < 2 * N_REL) ? (Wr + (size_t)(bb - N_REL) * 65536)
                     : Ws;
    wt[idx] = f2bf(src[i * 256 + o]);
  } else {
    int i = (b - PREP_XB - PREP_WB) * 256 + threadIdx.x;
    if (i < N_NODES) cnt[i] = 0;
  }
}

// one edge pass: per-block rel histogram (LDS) + combined dst histogram
__global__ void hist_all_kernel(const int* __restrict__ rel,
                                const int* __restrict__ dep,
                                const int* __restrict__ gov,
                                int* __restrict__ block_counts,
                                int* __restrict__ cnt) {
  __shared__ int h[N_REL];
  if (threadIdx.x < N_REL) h[threadIdx.x] = 0;
  __syncthreads();
  int beg = blockIdx.x * SORT_CHUNK;
  int end = min(beg + SORT_CHUNK, N_EDGES);
  for (int e = beg + threadIdx.x; e < end; e += blockDim.x) {
    atomicAdd(&h[rel[e]], 1);
    atomicAdd(&cnt[dep[e]], 1);             // fwd msg -> dep
    atomicAdd(&cnt[gov[e]], 1);             // rev msg -> gov (same bins)
  }
  __syncthreads();
  if (threadIdx.x < N_REL)
    block_counts[blockIdx.x * N_REL + threadIdx.x] = h[threadIdx.x];
}

// block 0: rel scan -> rel_start + per-block rel cursors
// block 1: single-block exclusive scan over the 30000 combined dst bins
__global__ void scan_fused_kernel(const int* __restrict__ block_counts,
                                  const int* __restrict__ cnt,
                                  int* __restrict__ rel_start,
                                  int* __restrict__ block_offset,
                                  int* __restrict__ rp,
                                  int* __restrict__ cursor) {
  if (blockIdx.x == 0) {
    __shared__ int tot[N_REL];
    int r = threadIdx.x;
    if (r < N_REL) {
      int s = 0;
      for (int b = 0; b < SORT_BLOCKS; ++b) s += block_counts[b * N_REL + r];
      tot[r] = s;
    }
    __syncthreads();
    if (threadIdx.x == 0) {
      int s = 0;
      for (int i = 0; i < N_REL; ++i) { rel_start[i] = s; s += tot[i]; }
      rel_start[N_REL] = s;
    }
    __syncthreads();
    if (r < N_REL) {
      int run = rel_start[r];
      for (int b = 0; b < SORT_BLOCKS; ++b) {
        block_offset[b * N_REL + r] = run;
        run += block_counts[b * N_REL + r];
      }
    }
  } else {
    __shared__ int part[256];
    const int CH = (N_NODES + 255) / 256;  // 118
    int t = threadIdx.x;
    int b0 = t * CH;
    int s = 0;
    for (int i = 0; i < CH; ++i) {
      int j = b0 + i;
      if (j < N_NODES) s += cnt[j];
    }
    part[t] = s;
    __syncthreads();
    for (int off = 1; off < 256; off <<= 1) {
      int add = (t >= off) ? part[t - off] : 0;
      __syncthreads();
      part[t] += add;
      __syncthreads();
    }
    int run = (t == 0) ? 0 : part[t - 1];
    for (int i = 0; i < CH; ++i) {
      int j = b0 + i;
      if (j < N_NODES) { rp[j] = run; cursor[j] = run; run += cnt[j]; }
    }
    if (t == 255) rp[N_NODES] = run;
  }
}

// rel-scatter producing perm AND the combined dst-keyed col list
// col value: msg row index (pos for fwd, N_EDGES+pos for rev)
__global__ void scatter_all_kernel(const int* __restrict__ rel,
                                   const int* __restrict__ dep,
                                   const int* __restrict__ gov,
                                   const int* __restrict__ block_offset,
                                   int* __restrict__ cursor,
                                   int* __restrict__ perm,
                                   int* __restrict__ col) {
  __shared__ int cur[N_REL];
  if (threadIdx.x < N_REL)
    cur[threadIdx.x] = block_offset[blockIdx.x * N_REL + threadIdx.x];
  __syncthreads();
  int beg = blockIdx.x * SORT_CHUNK;
  int end = min(beg + SORT_CHUNK, N_EDGES);
  for (int e = beg + threadIdx.x; e < end; e += blockDim.x) {
    int pos = atomicAdd(&cur[rel[e]], 1);  // LDS atomic, cheap
    perm[pos] = e;
    col[atomicAdd(&cursor[dep[e]], 1)] = pos;             // fwd msg -> dep
    col[atomicAdd(&cursor[gov[e]], 1)] = N_EDGES + pos;   // rev msg -> gov
  }
}

// ---- mega GEMM: buckets 0..9 fwd-edge, 10..19 rev-edge, 20 self ----------
// Edge buckets write bf16 msg rows (linear slots) in C/D-permuted column
// order: short at row*DIM + nb + lm*4 + i holds col nb + i*16 + lm.
// Self bucket writes fp32 directly to out (initializes it for reduce's RMW).

__global__ __launch_bounds__(256, 2)
void mega_gemm_kernel(const unsigned short* __restrict__ xbf,
                      const unsigned short* __restrict__ wt,
                      const float* __restrict__ b_self,
                      const float* __restrict__ b_fwd,
                      const float* __restrict__ b_rev,
                      const int* __restrict__ perm,
                      const int* __restrict__ rel_start,
                      const int* __restrict__ dep,
                      const int* __restrict__ gov,
                      unsigned short* __restrict__ msg,
                      float* __restrict__ out) {
  const int bkt = blockIdx.y;
  const bool is_self = (bkt == 2 * N_REL);
  const int r = bkt % N_REL;
  const bool fwd = bkt < N_REL;

  int beg, cnt;
  const int* src_idx = fwd ? gov : dep;
  unsigned short* mdir = msg + (fwd ? 0 : (size_t)N_EDGES * DIM);
  if (is_self) { beg = 0; cnt = N_NODES; }
  else { beg = rel_start[r]; cnt = rel_start[r + 1] - beg; }
  const int ntiles = (cnt + 63) >> 6;

  const int tid = threadIdx.x;
  const int wave = tid >> 6, lane = tid & 63;
  const int lm = lane & 15, q = lane >> 4;
  const int nb = wave * 64;

  __shared__ int s_src[64];
  __shared__ unsigned short sA[64 * A_STRIDE];  // 35840 B

  // hoisted, tile-invariant W fragments (128 VGPRs)
  bf16x8 wf[8][4];
  const unsigned short* wbase = wt + (size_t)bkt * DIM * DIM;
  #pragma unroll
  for (int kk = 0; kk < 8; ++kk)
    #pragma unroll
    for (int ni = 0; ni < 4; ++ni)
      wf[kk][ni] = *reinterpret_cast<const bf16x8*>(
          wbase + (size_t)(nb + ni * 16 + lm) * DIM + kk * 32 + q * 8);

  const float* bptr = is_self ? b_self : ((fwd ? b_fwd : b_rev) + r * DIM);
  float bias[4];
  #pragma unroll
  for (int ni = 0; ni < 4; ++ni) bias[ni] = bptr[nb + ni * 16 + lm];

  for (int t = blockIdx.x; t < ntiles; t += gridDim.x) {
    const int tile0 = t << 6;
    const int rows_valid = min(64, cnt - tile0);

    if (tid < 64) {
      int s;
      if (is_self) {
        int rr = tile0 + tid;
        s = rr < N_NODES ? rr : N_NODES - 1;
      } else {
        s = (tid < rows_valid) ? src_idx[perm[beg + tile0 + tid]] : 0;
      }
      s_src[tid] = s;
    }
    __syncthreads();

    // stage 64 gathered x rows into LDS (each row fetched exactly once)
    {
      int half = lane >> 5;        // 0 or 1
      int lcol = lane & 31;        // 16B chunk index within row
      #pragma unroll
      for (int i = 0; i < 8; ++i) {
        int row = wave * 16 + i * 2 + half;
        uint4 v = *reinterpret_cast<const uint4*>(
            xbf + (size_t)s_src[row] * DIM + lcol * 8);
        *reinterpret_cast<uint4*>(sA + row * A_STRIDE + lcol * 8) = v;
      }
    }
    __syncthreads();

    f32x4 acc[4][4];
    #pragma unroll
    for (int mi = 0; mi < 4; ++mi)
      #pragma unroll
      for (int ni = 0; ni < 4; ++ni)
        acc[mi][ni] = (f32x4){0.f, 0.f, 0.f, 0.f};

    // pure LDS-read + MFMA k-loop (W is in registers)
    #pragma unroll
    for (int kk = 0; kk < 8; ++kk) {
      bf16x8 a[4];
      #pragma unroll
      for (int mi = 0; mi < 4; ++mi)
        a[mi] = *reinterpret_cast<const bf16x8*>(
            sA + (mi * 16 + lm) * A_STRIDE + kk * 32 + q * 8);
      #pragma unroll
      for (int mi = 0; mi < 4; ++mi)
        #pragma unroll
        for (int ni = 0; ni < 4; ++ni)
          acc[mi][ni] = __builtin_amdgcn_mfma_f32_16x16x32_bf16(a[mi], wf[kk][ni], acc[mi][ni], 0, 0, 0);
    }

    if (is_self) {
      // direct fp32 stores to out (C/D layout; row = quad*4 + reg)
      #pragma unroll
      for (int mi = 0; mi < 4; ++mi) {
        #pragma unroll
        for (int reg = 0; reg < 4; ++reg) {
          int row = mi * 16 + q * 4 + reg;
          if (row < rows_valid) {
            #pragma unroll
            for (int ni = 0; ni < 4; ++ni)
              out[(size_t)(tile0 + row) * DIM + nb + ni * 16 + lm] =
                  acc[mi][ni][reg] + bias[ni];
          }
        }
      }
    } else {
      // permuted uint2 bf16 stores to linear msg slots
      #pragma unroll
      for (int mi = 0; mi < 4; ++mi) {
        #pragma unroll
        for (int reg = 0; reg < 4; ++reg) {
          int row = mi * 16 + q * 4 + reg;
          if (row < rows_valid) {
            unsigned int p0 = ((unsigned int)f2bf(acc[mi][1][reg] + bias[1]) << 16) |
                              f2bf(acc[mi][0][reg] + bias[0]);
            unsigned int p1 = ((unsigned int)f2bf(acc[mi][3][reg] + bias[3]) << 16) |
                              f2bf(acc[mi][2][reg] + bias[2]);
            uint2 u; u.x = p0; u.y = p1;
            *reinterpret_cast<uint2*>(
                mdir + (size_t)(beg + tile0 + row) * DIM + nb + lm * 4) = u;
          }
        }
      }
    }
    __syncthreads();  // protect s_src/sA for next tile
  }
}

// ---- phase 2: combined CSR gather-sum, 8-row parallel, uint4 loads -------

__global__ void reduce_kernel(const unsigned short* __restrict__ msg,
                              const int* __restrict__ rp,
                              const int* __restrict__ col,
                              float* __restrict__ out) {
  const int n = blockIdx.x, t = threadIdx.x;
  const int g = t >> 6, lane = t & 63;
  const int half = lane >> 5, l = lane & 31;
  const int grp = g * 2 + half;          // 8 row-groups
  const int beg = rp[n], end = rp[n + 1];
  if (end <= beg) return;

  float a[8];
  #pragma unroll
  for (int k = 0; k < 8; ++k) a[k] = 0.f;

  // group grp handles rows beg+grp, +8, ... ; 32 lanes x 16B = full 512B row
  for (int j = beg + grp; j < end; j += 8) {
    int row = col[j];
    uint4 v = *reinterpret_cast<const uint4*>(msg + (size_t)row * DIM + l * 8);
    union { unsigned int u; float f; } c;
    c.u = v.x << 16;          a[0] += c.f;
    c.u = v.x & 0xffff0000u;  a[1] += c.f;
    c.u = v.y << 16;          a[2] += c.f;
    c.u = v.y & 0xffff0000u;  a[3] += c.f;
    c.u = v.z << 16;          a[4] += c.f;
    c.u = v.z & 0xffff0000u;  a[5] += c.f;
    c.u = v.w << 16;          a[6] += c.f;
    c.u = v.w & 0xffff0000u;  a[7] += c.f;
  }

  // invert the storage permutation: position p = l*8+k within the row holds
  // column nb + i*16 + lm with nb=(p>>6)<<6, lm=(p&63)>>2, i=p&3
  __shared__ float part[8][DIM];
  const int nb = (l >> 3) << 6;
  #pragma unroll
  for (int k = 0; k < 8; ++k) {
    int lm = (l & 7) * 2 + (k >> 2);
    int i = k & 3;
    part[grp][nb + i * 16 + lm] = a[k];
  }
  __syncthreads();
  float s = 0.f;
  #pragma unroll
  for (int k = 0; k < 8; ++k) s += part[k][t];
  out[(size_t)n * DIM + t] += s;
}

// ---- fallback: single-phase atomic scatter (if ws too small) -------------

__global__ __launch_bounds__(256, 2)
void self_gemm_kernel(const unsigned short* __restrict__ xbf,
                      const unsigned short* __restrict__ wt_self,
                      const float* __restrict__ b_self,
                      float* __restrict__ out) {
  const int tid = threadIdx.x;
  const int wave = tid >> 6, lane = tid & 63;
  const int lm = lane & 15, q = lane >> 4;
  const int nb = wave * 64;

  bf16x8 wf[8][4];
  #pragma unroll
  for (int kk = 0; kk < 8; ++kk)
    #pragma unroll
    for (int ni = 0; ni < 4; ++ni)
      wf[kk][ni] = *reinterpret_cast<const bf16x8*>(
          wt_self + (size_t)(nb + ni * 16 + lm) * DIM + kk * 32 + q * 8);

  float bias[4];
  #pragma unroll
  for (int ni = 0; ni < 4; ++ni) bias[ni] = b_self[nb + ni * 16 + lm];

  const int ntiles = (N_NODES + 63) / 64;
  for (int t = blockIdx.x; t < ntiles; t += gridDim.x) {
    const int row0 = t * 64;
    const unsigned short* xr[4];
    #pragma unroll
    for (int mi = 0; mi < 4; ++mi) {
      int r = row0 + mi * 16 + lm;
      int rc = r < N_NODES ? r : N_NODES - 1;
      xr[mi] = xbf + (size_t)rc * DIM + q * 8;
    }

    f32x4 acc[4][4];
    #pragma unroll
    for (int mi = 0; mi < 4; ++mi)
      #pragma unroll
      for (int ni = 0; ni < 4; ++ni)
        acc[mi][ni] = (f32x4){0.f, 0.f, 0.f, 0.f};

    #pragma unroll
    for (int kk = 0; kk < 8; ++kk) {
      bf16x8 a[4];
      #pragma unroll
      for (int mi = 0; mi < 4; ++mi)
        a[mi] = *reinterpret_cast<const bf16x8*>(xr[mi] + kk * 32);
      #pragma unroll
      for (int mi = 0; mi < 4; ++mi)
        #pragma unroll
        for (int ni = 0; ni < 4; ++ni)
          acc[mi][ni] = __builtin_amdgcn_mfma_f32_16x16x32_bf16(a[mi], wf[kk][ni], acc[mi][ni], 0, 0, 0);
    }

    #pragma unroll
    for (int mi = 0; mi < 4; ++mi) {
      #pragma unroll
      for (int reg = 0; reg < 4; ++reg) {
        int row = row0 + mi * 16 + q * 4 + reg;
        if (row < N_NODES) {
          #pragma unroll
          for (int ni = 0; ni < 4; ++ni)
            out[(size_t)row * DIM + nb + ni * 16 + lm] = acc[mi][ni][reg] + bias[ni];
        }
      }
    }
  }
}

__global__ void edge_gemm_atomic_kernel(const unsigned short* __restrict__ xbf,
                                        const unsigned short* __restrict__ wt,
                                        const float* __restrict__ b_fwd,
                                        const float* __restrict__ b_rev,
                                        const int* __restrict__ perm,
                                        const int* __restrict__ rel_start,
                                        const int* __restrict__ dep,
                                        const int* __restrict__ gov,
                                        float* __restrict__ out) {
  const int bucket = blockIdx.y;
  const int r = bucket % N_REL;
  const bool fwd = bucket < N_REL;
  const int beg = rel_start[r];
  const int cnt = rel_start[r + 1] - beg;
  const int ntiles = (cnt + 63) >> 6;

  const int tid = threadIdx.x;
  const int wave = tid >> 6, lane = tid & 63;
  const int lm = lane & 15, q = lane >> 4;
  const int nb = wave * 64;

  __shared__ int s_src[64], s_dst[64];

  const unsigned short* wr[4];
  #pragma unroll
  for (int ni = 0; ni < 4; ++ni)
    wr[ni] = wt + (size_t)bucket * DIM * DIM + (size_t)(nb + ni * 16 + lm) * DIM + q * 8;

  const float* bptr = (fwd ? b_fwd : b_rev) + r * DIM;
  float bias[4];
  #pragma unroll
  for (int ni = 0; ni < 4; ++ni) bias[ni] = bptr[nb + ni * 16 + lm];

  for (int t = blockIdx.x; t < ntiles; t += gridDim.x) {
    const int tile0 = t << 6;
    const int rows_valid = min(64, cnt - tile0);

    if (tid < 64) {
      int s = 0, d = -1;
      if (tid < rows_valid) {
        int e = perm[beg + tile0 + tid];
        int gv = gov[e], dp = dep[e];
        s = fwd ? gv : dp;
        d = fwd ? dp : gv;
      }
      s_src[tid] = s;
      s_dst[tid] = d;
    }
    __syncthreads();

    const unsigned short* xr[4];
    #pragma unroll
    for (int mi = 0; mi < 4; ++mi)
      xr[mi] = xbf + (size_t)s_src[mi * 16 + lm] * DIM + q * 8;

    f32x4 acc[4][4];
    #pragma unroll
    for (int mi = 0; mi < 4; ++mi)
      #pragma unroll
      for (int ni = 0; ni < 4; ++ni)
        acc[mi][ni] = (f32x4){0.f, 0.f, 0.f, 0.f};

    #pragma unroll
    for (int k0 = 0; k0 < DIM; k0 += 32) {
      bf16x8 a[4], b[4];
      #pragma unroll
      for (int mi = 0; mi < 4; ++mi) a[mi] = *reinterpret_cast<const bf16x8*>(xr[mi] + k0);
      #pragma unroll
      for (int ni = 0; ni < 4; ++ni) b[ni] = *reinterpret_cast<const bf16x8*>(wr[ni] + k0);
      #pragma unroll
      for (int mi = 0; mi < 4; ++mi)
        #pragma unroll
        for (int ni = 0; ni < 4; ++ni)
          acc[mi][ni] = __builtin_amdgcn_mfma_f32_16x16x32_bf16(a[mi], b[ni], acc[mi][ni], 0, 0, 0);
    }

    #pragma unroll
    for (int mi = 0; mi < 4; ++mi) {
      #pragma unroll
      for (int reg = 0; reg < 4; ++reg) {
        int row = mi * 16 + q * 4 + reg;
        if (row < rows_valid) {
          int dst = s_dst[row];
          float* op = out + (size_t)dst * DIM + nb + lm;
          #pragma unroll
          for (int ni = 0; ni < 4; ++ni)
            atomicAdd(op + ni * 16, acc[mi][ni][reg] + bias[ni]);
        }
      }
    }
    __syncthreads();
  }
}

// ---- launch --------------------------------------------------------------

extern "C" void kernel_launch(void* const* d_in, const int* in_sizes, int n_in,
                              void* d_out, int out_size, void* d_ws, size_t ws_size,
                              hipStream_t stream) {
  const float* x      = (const float*)d_in[0];
  const float* W_self = (const float*)d_in[1];
  const float* b_self = (const float*)d_in[2];
  const float* W_fwd  = (const float*)d_in[3];
  const float* b_fwd  = (const float*)d_in[4];
  const float* W_rev  = (const float*)d_in[5];
  const float* b_rev  = (const float*)d_in[6];
  const int* dep = (const int*)d_in[7];
  const int* rel = (const int*)d_in[8];
  const int* gov = (const int*)d_in[9];
  float* out = (float*)d_out;

  char* base = (char*)d_ws;
  size_t off = 0;
  auto alloc = [&](size_t bytes) -> char* {
    char* p = base + off;
    off = (off + bytes + 15) & ~(size_t)15;
    return p;
  };

  unsigned short* xbf = (unsigned short*)alloc((size_t)N_NODES * DIM * 2);   // 15.36 MB
  unsigned short* wt  = (unsigned short*)alloc((size_t)21 * DIM * DIM * 2);  // 2.75 MB
  int* perm          = (int*)alloc((size_t)N_EDGES * 4);
  int* rel_start     = (int*)alloc(16 * 4);
  int* block_counts  = (int*)alloc(SORT_BLOCKS * N_REL * 4);
  int* block_offset  = (int*)alloc(SORT_BLOCKS * N_REL * 4);
  int* cnt    = (int*)alloc((size_t)N_NODES * 4);
  int* rp     = (int*)alloc((size_t)(N_NODES + 1) * 4);
  int* cursor = (int*)alloc((size_t)N_NODES * 4);
  int* col    = (int*)alloc((size_t)2 * N_EDGES * 4);
  unsigned short* msg = (unsigned short*)alloc((size_t)2 * N_EDGES * DIM * 2);  // 153.6 MB
  const bool two_phase = (off <= ws_size);

  prep_kernel<<<PREP_XB + PREP_WB + PREP_ZB, 256, 0, stream>>>(
      x, W_fwd, W_rev, W_self, xbf, wt, cnt);
  hist_all_kernel<<<SORT_BLOCKS, 256, 0, stream>>>(rel, dep, gov, block_counts, cnt);
  scan_fused_kernel<<<2, 256, 0, stream>>>(
      block_counts, cnt, rel_start, block_offset, rp, cursor);
  scatter_all_kernel<<<SORT_BLOCKS, 256, 0, stream>>>(
      rel, dep, gov, block_offset, cursor, perm, col);

  if (two_phase) {
    // buckets 0..19 edges -> msg; bucket 20 self -> out (init for reduce RMW)
    mega_gemm_kernel<<<dim3(48, 2 * N_REL + 1), 256, 0, stream>>>(
        xbf, wt, b_self, b_fwd, b_rev, perm, rel_start, dep, gov, msg, out);
    reduce_kernel<<<N_NODES, 256, 0, stream>>>(msg, rp, col, out);
  } else {
    self_gemm_kernel<<<120, 256, 0, stream>>>(
        xbf, wt + (size_t)20 * DIM * DIM, b_self, out);
    edge_gemm_atomic_kernel<<<dim3(260, 20), 256, 0, stream>>>(
        xbf, wt, b_fwd, b_rev, perm, rel_start, dep, gov, out);
  }
}